// Round 6
// baseline (235.621 us; speedup 1.0000x reference)
//
#include <hip/hip_runtime.h>
#include <hip/hip_bf16.h>

#define B_   4
#define M_   8192
#define N_   32768
#define H_   128
#define EPS_ 1e-5f
#define TBL  1048576   // 4 * 64^3 dense hash table
#define GUARD 8192     // negative-offset guard for window probes

typedef short short8 __attribute__((ext_vector_type(8)));   // 8 bf16 (4 VGPRs)
typedef float f32x4  __attribute__((ext_vector_type(4)));   // 4 fp32 acc

// ---------------------------------------------------------------- prep
__global__ __launch_bounds__(256) void prep_kernel(const int* __restrict__ coords,
                                                   int* __restrict__ table,
                                                   int* __restrict__ packed,
                                                   int* __restrict__ keyb,
                                                   float* __restrict__ gsum,
                                                   unsigned int* __restrict__ hbz) {
    int n = blockIdx.x * 256 + threadIdx.x;
    int b = coords[4*n+0], x = coords[4*n+1], y = coords[4*n+2], z = coords[4*n+3];
    packed[n] = (x << 10) | (y << 5) | z;
    int key = ((b*64 + x+1)*64 + y+1)*64 + (z+1);
    keyb[n] = key;
    table[key] = n;
    if (blockIdx.x == 0) gsum[threadIdx.x] = 0.f;            // 256 floats (BN2 stats acc)
    if (blockIdx.x == 1 && threadIdx.x < 64) hbz[threadIdx.x] = 0u;  // 256B zero row
}

// ---------------------------------------------------------------- w3 -> bf16 MFMA B-fragment layout
// w3f[t*8+j], t = (o<<11)|(ks<<9)|(ct<<6)|lane :
//   value = bf16(w3[o][c][n]), c = ks*32 + (lane>>4)*8 + j, n = ct*16 + (lane&15)
__global__ __launch_bounds__(256) void w3pack_kernel(const float* __restrict__ w3,
                                                     ushort* __restrict__ w3f) {
    int t = blockIdx.x * 256 + threadIdx.x;   // 27*2048 = 55296 threads exactly
    int lane = t & 63;
    int ct   = (t >> 6) & 7;
    int ks   = (t >> 9) & 3;
    int o    = t >> 11;
    int quad = lane >> 4, l15 = lane & 15;
    int n = ct*16 + l15;
    const float* src = w3 + o*16384;
    ushort out8[8];
#pragma unroll
    for (int j = 0; j < 8; ++j) {
        int c = ks*32 + quad*8 + j;
        float v = src[c*128 + n];
        __hip_bfloat16 bv = __float2bfloat16(v);
        ushort u; __builtin_memcpy(&u, &bv, 2);
        out8[j] = u;
    }
    *(uint4*)&w3f[t*8] = *(uint4*)out8;
}

// ---------------------------------------------------------------- kNN via radius-2 window
__global__ __launch_bounds__(256) void knn_window_kernel(const int* __restrict__ table,
                                                         const int* __restrict__ keyb,
                                                         int* __restrict__ nbr,
                                                         int* __restrict__ flagcnt,
                                                         int* __restrict__ flaglist) {
    __shared__ int okey_sh[125], d2_sh[125];
    __shared__ int tops[256 * 8];
    int tid = threadIdx.x;
    if (tid < 125) {
        int dx = tid / 25 - 2, rr = tid % 25, dy = rr / 5 - 2, dz = rr % 5 - 2;
        okey_sh[tid] = dx * 4096 + dy * 64 + dz;
        d2_sh[tid]   = dx*dx + dy*dy + dz*dz;
    }
    __syncthreads();

    int q   = blockIdx.x * 64 + (tid >> 2);
    int sub = tid & 3;
    int kb  = keyb[q];

    int top[8];
#pragma unroll
    for (int k = 0; k < 8; ++k) top[k] = 0x7FFFFFFF;

    int base = sub * 32;
    int cnt  = (sub == 3) ? 29 : 32;
    for (int i = 0; i < cnt; ++i) {
        int idx = base + i;
        int j = table[kb + okey_sh[idx]];
        if (j >= 0) {
            int key = (d2_sh[idx] << 13) | (j & 8191);
            if (key < top[7]) {
#pragma unroll
                for (int k = 7; k >= 1; --k)
                    top[k] = (key < top[k]) ? max(key, top[k-1]) : top[k];
                top[0] = min(key, top[0]);
            }
        }
    }
#pragma unroll
    for (int k = 0; k < 8; ++k) tops[tid*8 + k] = top[k];
    __syncthreads();

    if (sub == 0) {
        const int* L = &tops[tid*8];
        int ia0 = 0, ia1 = 0, ia2 = 0, ia3 = 0;
        int res[8];
#pragma unroll
        for (int k = 0; k < 8; ++k) {
            int v0 = L[ia0], v1 = L[8 + ia1], v2 = L[16 + ia2], v3 = L[24 + ia3];
            int m01 = min(v0, v1), m23 = min(v2, v3);
            int m = min(m01, m23);
            res[k] = m;
            if (m == v0) ++ia0; else if (m == v1) ++ia1;
            else if (m == v2) ++ia2; else ++ia3;
        }
        int bb = q & ~(M_-1);
        if ((res[7] >> 13) <= 8) {
#pragma unroll
            for (int k = 0; k < 8; ++k) nbr[q*8 + k] = bb + (res[k] & 8191);
        } else {
            int pos = atomicAdd(flagcnt, 1);
            flaglist[pos] = q;
        }
    }
}

// ---------------------------------------------------------------- brute-force cleanup
__global__ __launch_bounds__(256) void knn_bf_kernel(const int* __restrict__ packed,
                                                     const int* __restrict__ flagcnt,
                                                     const int* __restrict__ flaglist,
                                                     int* __restrict__ nbr) {
    __shared__ int tops[256 * 8];
    int tid = threadIdx.x;
    int cnt = *flagcnt;
    for (int f = blockIdx.x; f < cnt; f += gridDim.x) {
        int n = flaglist[f];
        int bb = n & ~(M_-1);
        int p = packed[n];
        int qx = (p >> 10) & 31, qy = (p >> 5) & 31, qz = p & 31;
        int top[8];
#pragma unroll
        for (int k = 0; k < 8; ++k) top[k] = 0x7FFFFFFF;
        for (int j = tid; j < M_; j += 256) {
            int c = packed[bb + j];
            int dx = qx - ((c >> 10) & 31);
            int dy = qy - ((c >> 5) & 31);
            int dz = qz - (c & 31);
            int d2 = dx*dx + dy*dy + dz*dz;
            int key = (d2 << 13) | j;
            if (key < top[7]) {
#pragma unroll
                for (int k = 7; k >= 1; --k)
                    top[k] = (key < top[k]) ? max(key, top[k-1]) : top[k];
                top[0] = min(key, top[0]);
            }
        }
#pragma unroll
        for (int k = 0; k < 8; ++k) tops[tid*8 + k] = top[k];
        __syncthreads();
        for (int stride = 128; stride >= 1; stride >>= 1) {
            if (tid < stride) {
                int* A  = &tops[tid*8];
                int* Bp = &tops[(tid+stride)*8];
                int r[8]; int ia = 0, ib = 0;
#pragma unroll
                for (int k = 0; k < 8; ++k) {
                    int a = A[ia], b2 = Bp[ib];
                    if (a <= b2) { r[k] = a; ++ia; } else { r[k] = b2; ++ib; }
                }
#pragma unroll
                for (int k = 0; k < 8; ++k) A[k] = r[k];
            }
            __syncthreads();
        }
        if (tid == 0) {
#pragma unroll
            for (int k = 0; k < 8; ++k) nbr[n*8 + k] = bb + (tops[k] & 8191);
        }
        __syncthreads();
    }
}

// ---------------------------------------------------------------- 1x1 conv (combined @ w1)
__global__ __launch_bounds__(256) void h1_kernel(const float* __restrict__ feats,
                                                 const int* __restrict__ nbr,
                                                 const float* __restrict__ w1,
                                                 float* __restrict__ hpre) {
    __shared__ float comb[16][72];
    int tid = threadIdx.x;
    int rowbase = blockIdx.x * 16;
    if (tid < 144) {
        int r = tid / 9, s = tid % 9;
        int grow = rowbase + r;
        int idx = (s == 0) ? grow : nbr[grow*8 + (s-1)];
        const float4* f = (const float4*)(feats + idx * 8);
        float4 a = f[0], b = f[1];
        float* dp = &comb[r][s*8];
        dp[0]=a.x; dp[1]=a.y; dp[2]=a.z; dp[3]=a.w;
        dp[4]=b.x; dp[5]=b.y; dp[6]=b.z; dp[7]=b.w;
    }
    __syncthreads();
    int c = tid & 127, rh = tid >> 7;
    float acc[8];
#pragma unroll
    for (int i = 0; i < 8; ++i) acc[i] = 0.f;
    for (int s = 0; s < 72; ++s) {
        float w = w1[s*128 + c];
#pragma unroll
        for (int i = 0; i < 8; ++i)
            acc[i] += comb[rh*8 + i][s] * w;
    }
#pragma unroll
    for (int i = 0; i < 8; ++i)
        hpre[(rowbase + rh*8 + i)*128 + c] = acc[i];
}

// ---------------------------------------------------------------- BN stats (h1 path)
__global__ __launch_bounds__(256) void reduce_kernel(const float* __restrict__ src,
                                                     float* __restrict__ part) {
    __shared__ float ssum[256], ssq[256];
    int tid = threadIdx.x;
    int c = tid & 127, halfr = tid >> 7;
    int rowbase = blockIdx.x * 128 + halfr * 64;
    float s = 0.f, q = 0.f;
    for (int i = 0; i < 64; ++i) {
        float v = src[(rowbase + i)*128 + c];
        s += v; q += v*v;
    }
    ssum[tid] = s; ssq[tid] = q;
    __syncthreads();
    if (tid < 128) {
        part[blockIdx.x*256 + tid]       = ssum[tid] + ssum[tid+128];
        part[blockIdx.x*256 + 128 + tid] = ssq[tid]  + ssq[tid+128];
    }
}

__global__ __launch_bounds__(128) void stats_kernel(const float* __restrict__ part,
                                                    const float* __restrict__ g,
                                                    const float* __restrict__ bias,
                                                    float* __restrict__ scale,
                                                    float* __restrict__ shift) {
    int c = threadIdx.x;
    float s = 0.f, q = 0.f;
    for (int b = 0; b < 256; ++b) {
        s += part[b*256 + c];
        q += part[b*256 + 128 + c];
    }
    float mu  = s / (float)N_;
    float var = q / (float)N_ - mu*mu;
    float inv = rsqrtf(var + EPS_);
    float sc  = inv * g[c];
    scale[c] = sc;
    shift[c] = bias[c] - mu * sc;
}

// BN2 stats from direct sums (conv3 epilogue accumulates gsum)
__global__ __launch_bounds__(128) void stats2_kernel(const float* __restrict__ gsum,
                                                     const float* __restrict__ g,
                                                     const float* __restrict__ bias,
                                                     float* __restrict__ scale,
                                                     float* __restrict__ shift) {
    int c = threadIdx.x;
    float s = gsum[c], q = gsum[128 + c];
    float mu  = s / (float)N_;
    float var = q / (float)N_ - mu*mu;
    float inv = rsqrtf(var + EPS_);
    float sc  = inv * g[c];
    scale[c] = sc;
    shift[c] = bias[c] - mu * sc;
}

// BN+ReLU -> bf16 output (for conv3 A operand)
__global__ __launch_bounds__(256) void bnrelu_bf16_kernel(const float* __restrict__ x,
                                                          const float* __restrict__ scale,
                                                          const float* __restrict__ shift,
                                                          ushort* __restrict__ y) {
    int i = blockIdx.x * 256 + threadIdx.x;
    float4 v = ((const float4*)x)[i];
    int c = (i * 4) & 127;
    v.x = fmaxf(0.f, v.x*scale[c]   + shift[c]);
    v.y = fmaxf(0.f, v.y*scale[c+1] + shift[c+1]);
    v.z = fmaxf(0.f, v.z*scale[c+2] + shift[c+2]);
    v.w = fmaxf(0.f, v.w*scale[c+3] + shift[c+3]);
    ushort o[4];
#pragma unroll
    for (int k = 0; k < 4; ++k) {
        float f = (&v.x)[k];
        __hip_bfloat16 bv = __float2bfloat16(f);
        __builtin_memcpy(&o[k], &bv, 2);
    }
    ((ushort4*)y)[i] = make_ushort4(o[0], o[1], o[2], o[3]);
}

// ---------------------------------------------------------------- 3^3 sparse conv: bf16 MFMA gather-GEMM
// R6 = R5 design with the B-ring race fixed: ALL staging issues happen AFTER the
// per-iter barrier (R4 ordering). Ledger: at loop top only B(o)'s 4 GLLs are
// outstanding (A(o) drained by compiler wait at the aC<-aN rotation, post-compute)
// -> vmcnt(0) is ~free; barrier; then issue A(o+1) (first) + B(o+1) (second) so
// the rotation wait leaves B in flight; compute(o).
// A: global->REGISTER direct (no LDS round trip). B: 2x32KB LDS ring, fragment-major.
#define CONV3_LDS 79872
#define GLL(src, dst) __builtin_amdgcn_global_load_lds( \
    (const __attribute__((address_space(1))) unsigned int*)(src), \
    (__attribute__((address_space(3))) unsigned int*)(dst), 16, 0, 0)

__device__ __forceinline__ int okey_of(int o) {
    int dx = o/9 - 1, dy = (o/3)%3 - 1, dz = o%3 - 1;
    return dx*4096 + dy*64 + dz;
}

__global__ __launch_bounds__(512) void conv3_mfma_kernel(const ushort* __restrict__ hb,
                                                         const ushort* __restrict__ w3f,
                                                         const int* __restrict__ table,
                                                         const int* __restrict__ keyb,
                                                         float* __restrict__ h2,
                                                         float* __restrict__ gsum) {
    extern __shared__ char smem_raw[];
    // B ring: 2 x 32768 B at offset 0 ; jsh: 27*128*4 = 13824 B at 65536
    int* jsh = (int*)(smem_raw + 65536);
    int tid = threadIdx.x;
    int lane = tid & 63, wid = tid >> 6;
    int quad = lane >> 4, l15 = lane & 15;
    int bid = blockIdx.x;
    int swz = (bid & 7) * 32 + (bid >> 3);   // XCD-chunked, bijective (256 % 8 == 0)
    int rowbase = swz * 128;
    int wr = wid >> 1;              // row group 0..3 (32 rows each)
    int cb = (wid & 1) * 4;         // col-tile base (0 or 4)

    // all 27x128 table lookups -> jsh (invalid stays -1 -> zero row at hb - 128)
    for (int t = tid; t < 27*128; t += 512) {
        int o = t >> 7, r = t & 127;
        jsh[t] = table[keyb[rowbase + r] + okey_of(o)];
    }
    __syncthreads();

    int row0 = wr*32 + l15;          // this lane's A rows (tile i=0 / i=1)
    int row1 = row0 + 16;

    // prologue: A(0) -> aC registers, B(0) -> LDS slot 0
    short8 aC[8], aN[8];
    {
        int j0 = jsh[row0], j1 = jsh[row1];
        const ushort* p0 = hb + j0*128 + quad*8;
        const ushort* p1 = hb + j1*128 + quad*8;
#pragma unroll
        for (int ks = 0; ks < 4; ++ks) {
            aC[ks*2+0] = *(const short8*)(p0 + ks*32);
            aC[ks*2+1] = *(const short8*)(p1 + ks*32);
        }
    }
#pragma unroll
    for (int i = 0; i < 4; ++i) {
        int flat = i*512 + tid;
        GLL(w3f + flat*8, smem_raw + (flat << 4));
    }

    f32x4 acc[2][4];
#pragma unroll
    for (int i = 0; i < 2; ++i)
#pragma unroll
        for (int c = 0; c < 4; ++c)
            acc[i][c] = (f32x4){0.f, 0.f, 0.f, 0.f};

#pragma unroll 1
    for (int o = 0; o < 27; ++o) {
        // B(o) landed (only its 4 GLLs are outstanding; A drained at prior rotation)
        asm volatile("s_waitcnt vmcnt(0)" ::: "memory");
        __builtin_amdgcn_s_barrier();
        __builtin_amdgcn_sched_barrier(0);
        // all waves past compute(o-1) -> safe to overwrite slot (o+1)&1
        int on = (o+1 < 27) ? o+1 : 26;
        // issue A(o+1) -> aN registers (8 global_load_dwordx4; 16 rows x 64B lines)
        {
            int jn0 = jsh[on*128 + row0], jn1 = jsh[on*128 + row1];
            const ushort* p0 = hb + jn0*128 + quad*8;
            const ushort* p1 = hb + jn1*128 + quad*8;
#pragma unroll
            for (int ks = 0; ks < 4; ++ks) {
                aN[ks*2+0] = *(const short8*)(p0 + ks*32);
                aN[ks*2+1] = *(const short8*)(p1 + ks*32);
            }
        }
        // issue B(o+1) stage -> other ring slot (4 global_load_lds dwordx4)
        {
            const ushort* wsrc = w3f + (on << 14);
            char* bdst = smem_raw + (((o+1) & 1) << 15);
#pragma unroll
            for (int i = 0; i < 4; ++i) {
                int flat = i*512 + tid;
                GLL(wsrc + flat*8, bdst + (flat << 4));
            }
        }
        // compute(o): registers + conflict-free ds_read_b128 only
        const ushort* Bc = (const ushort*)(smem_raw + ((o & 1) << 15));
#pragma unroll
        for (int ks = 0; ks < 4; ++ks) {
            short8 bfr[4];
#pragma unroll
            for (int c = 0; c < 4; ++c)
                bfr[c] = *(const short8*)&Bc[((ks*8 + cb + c)*64 + lane) << 3];
#pragma unroll
            for (int c = 0; c < 4; ++c) {
                acc[0][c] = __builtin_amdgcn_mfma_f32_16x16x32_bf16(aC[ks*2+0], bfr[c], acc[0][c], 0, 0, 0);
                acc[1][c] = __builtin_amdgcn_mfma_f32_16x16x32_bf16(aC[ks*2+1], bfr[c], acc[1][c], 0, 0, 0);
            }
        }
        // rotate A registers (compiler waits vmcnt here for aN; B(o+1) stays in flight)
#pragma unroll
        for (int k = 0; k < 8; ++k) aC[k] = aN[k];
    }

    __syncthreads();   // full drain before LDS reuse

    // epilogue: store h2 + per-column BN2 partial sums
    float s[4], q[4];
#pragma unroll
    for (int c = 0; c < 4; ++c) { s[c] = 0.f; q[c] = 0.f; }
#pragma unroll
    for (int i = 0; i < 2; ++i)
#pragma unroll
        for (int c = 0; c < 4; ++c)
#pragma unroll
            for (int r = 0; r < 4; ++r) {
                int row = rowbase + wr*32 + i*16 + quad*4 + r;
                int col = (cb + c)*16 + l15;
                float v = acc[i][c][r];
                h2[row*128 + col] = v;
                s[c] += v; q[c] += v*v;
            }
    float* red = (float*)smem_raw;   // 256 floats: sums[128] | sqs[128]
    if (tid < 256) red[tid] = 0.f;
    __syncthreads();
#pragma unroll
    for (int c = 0; c < 4; ++c) {
        int col = (cb + c)*16 + l15;
        atomicAdd(&red[col], s[c]);
        atomicAdd(&red[128 + col], q[c]);
    }
    __syncthreads();
    if (tid < 256) atomicAdd(&gsum[tid], red[tid]);
}

// ---------------------------------------------------------------- final 1x1 conv, fused BN2+ReLU
// Stage BN'd rows in padded LDS (stride 129: conflict-free) + wout in LDS;
// float4 w-reads. Replaces ~134M scalar global loads (16x row duplication).
__global__ __launch_bounds__(256) void out_kernel(const float* __restrict__ h2,
                                                  const float* __restrict__ wout,
                                                  const float* __restrict__ scale,
                                                  const float* __restrict__ shift,
                                                  float* __restrict__ out) {
    __shared__ float hrow[128][129];
    __shared__ float wsh[2048];
    __shared__ float sc[128], sh[128];
    int tid = threadIdx.x;
    if (tid < 128) { sc[tid] = scale[tid]; sh[tid] = shift[tid]; }
#pragma unroll
    for (int i = 0; i < 8; ++i) wsh[i*256 + tid] = wout[i*256 + tid];
    __syncthreads();

    int rowbase = blockIdx.x * 128;
    // stage 128 rows, applying BN+ReLU once per element
#pragma unroll
    for (int i = 0; i < 16; ++i) {
        int flat = i*256 + tid;              // 4096 float4 chunks
        int row = flat >> 5, c4 = (flat & 31) * 4;
        float4 v = *(const float4*)&h2[(rowbase + row)*128 + c4];
        float4 scv = *(const float4*)&sc[c4];
        float4 shv = *(const float4*)&sh[c4];
        hrow[row][c4+0] = fmaxf(0.f, fmaf(v.x, scv.x, shv.x));
        hrow[row][c4+1] = fmaxf(0.f, fmaf(v.y, scv.y, shv.y));
        hrow[row][c4+2] = fmaxf(0.f, fmaf(v.z, scv.z, shv.z));
        hrow[row][c4+3] = fmaxf(0.f, fmaf(v.w, scv.w, shv.w));
    }
    __syncthreads();

    int row = tid >> 1, dbase = (tid & 1) * 8;
    float acc[8];
#pragma unroll
    for (int k = 0; k < 8; ++k) acc[k] = 0.f;
    for (int c = 0; c < 128; ++c) {
        float hv = hrow[row][c];
        float4 w0 = *(const float4*)&wsh[c*16 + dbase];
        float4 w1 = *(const float4*)&wsh[c*16 + dbase + 4];
        acc[0] = fmaf(hv, w0.x, acc[0]);
        acc[1] = fmaf(hv, w0.y, acc[1]);
        acc[2] = fmaf(hv, w0.z, acc[2]);
        acc[3] = fmaf(hv, w0.w, acc[3]);
        acc[4] = fmaf(hv, w1.x, acc[4]);
        acc[5] = fmaf(hv, w1.y, acc[5]);
        acc[6] = fmaf(hv, w1.z, acc[6]);
        acc[7] = fmaf(hv, w1.w, acc[7]);
    }
    float* op = out + (rowbase + row)*16 + dbase;
    *(float4*)op       = (float4){acc[0], acc[1], acc[2], acc[3]};
    *(float4*)(op + 4) = (float4){acc[4], acc[5], acc[6], acc[7]};
}

// ---------------------------------------------------------------- launch
extern "C" void kernel_launch(void* const* d_in, const int* in_sizes, int n_in,
                              void* d_out, int out_size, void* d_ws, size_t ws_size,
                              hipStream_t stream) {
    const int*   coords = (const int*)d_in[0];
    const float* feats  = (const float*)d_in[1];
    const float* w1     = (const float*)d_in[2];
    const float* g1     = (const float*)d_in[3];
    const float* b1     = (const float*)d_in[4];
    const float* w3     = (const float*)d_in[5];
    const float* g2     = (const float*)d_in[6];
    const float* b2     = (const float*)d_in[7];
    const float* wout   = (const float*)d_in[8];
    float* out = (float*)d_out;

    char* ws = (char*)d_ws;
    int*    table_base = (int*)(ws);                              // 4.03 MB
    int*    table   = table_base + GUARD;
    int*    packed  = (int*)(ws + (4352u<<10));                   // 128 KB
    int*    keyb    = (int*)(ws + (4608u<<10));                   // 128 KB
    int*    nbr     = (int*)(ws + (4864u<<10));                   // 1 MB
    int*    flagcnt = (int*)(ws + (5888u<<10));                   // 4 B
    int*    flaglist= (int*)(ws + (5892u<<10));                   // 128 KB
    float*  part    = (float*)(ws + (6144u<<10));                 // 256 KB (BN1 partials)
    float*  scale1  = (float*)(ws + (6400u<<10));
    float*  shift1  = scale1 + 128;
    float*  scale2  = shift1 + 128;
    float*  shift2  = scale2 + 128;
    float*  gsum    = (float*)(ws + (6416u<<10));                 // 1 KB (BN2 direct sums)
    ushort* w3f     = (ushort*)(ws + (6656u<<10));                // 0.88 MB (ends 7520K)
    ushort* hb      = (ushort*)(ws + (7680u<<10));                // 8 MB; hb-128 = 256B zero row
    float*  h       = (float*)(ws + (15872u<<10));                // 16 MB
    float*  h2      = h;   // aliased: h is dead once hb is written, conv3 reads only hb

    static bool conv3_attr_set = false;
    if (!conv3_attr_set) {
        hipFuncSetAttribute(reinterpret_cast<const void*>(&conv3_mfma_kernel),
                            hipFuncAttributeMaxDynamicSharedMemorySize, CONV3_LDS);
        conv3_attr_set = true;
    }

    hipMemsetAsync(table_base, 0xFF, (TBL + GUARD) * sizeof(int), stream);
    hipMemsetAsync(flagcnt, 0, sizeof(int), stream);
    prep_kernel      <<<N_/256, 256, 0, stream>>>(coords, table, packed, keyb,
                                                  gsum, (unsigned int*)(hb - 128));
    w3pack_kernel    <<<216, 256, 0, stream>>>(w3, w3f);
    knn_window_kernel<<<N_/64, 256, 0, stream>>>(table, keyb, nbr, flagcnt, flaglist);
    knn_bf_kernel    <<<256, 256, 0, stream>>>(packed, flagcnt, flaglist, nbr);
    h1_kernel        <<<N_/16, 256, 0, stream>>>(feats, nbr, w1, h);
    reduce_kernel    <<<N_/128, 256, 0, stream>>>(h, part);
    stats_kernel     <<<1, 128, 0, stream>>>(part, g1, b1, scale1, shift1);
    bnrelu_bf16_kernel<<<(N_*H_/4)/256, 256, 0, stream>>>(h, scale1, shift1, hb);
    conv3_mfma_kernel<<<N_/128, 512, CONV3_LDS, stream>>>(hb, w3f, table, keyb, h2, gsum);
    stats2_kernel    <<<1, 128, 0, stream>>>(gsum, g2, b2, scale2, shift2);
    out_kernel       <<<N_/128, 256, 0, stream>>>(h2, wout, scale2, shift2, out);
}

// Round 7
// 227.195 us; speedup vs baseline: 1.0371x; 1.0371x over previous
//
#include <hip/hip_runtime.h>
#include <hip/hip_bf16.h>

#define B_   4
#define M_   8192
#define N_   32768
#define H_   128
#define EPS_ 1e-5f
#define TBL  1048576   // 4 * 64^3 dense hash table
#define GUARD 8192     // negative-offset guard for window probes

typedef short short8 __attribute__((ext_vector_type(8)));   // 8 bf16 (4 VGPRs)
typedef float f32x4  __attribute__((ext_vector_type(4)));   // 4 fp32 acc

// ---------------------------------------------------------------- prep
__global__ __launch_bounds__(256) void prep_kernel(const int* __restrict__ coords,
                                                   int* __restrict__ table,
                                                   int* __restrict__ packed,
                                                   int* __restrict__ keyb,
                                                   float* __restrict__ gsum,
                                                   unsigned int* __restrict__ hbz) {
    int n = blockIdx.x * 256 + threadIdx.x;
    int b = coords[4*n+0], x = coords[4*n+1], y = coords[4*n+2], z = coords[4*n+3];
    packed[n] = (x << 10) | (y << 5) | z;
    int key = ((b*64 + x+1)*64 + y+1)*64 + (z+1);
    keyb[n] = key;
    table[key] = n;
    if (blockIdx.x == 0) gsum[threadIdx.x] = 0.f;            // 256 floats (BN2 stats acc)
    if (blockIdx.x == 1 && threadIdx.x < 64) hbz[threadIdx.x] = 0u;  // 256B zero row
}

// ---------------------------------------------------------------- w3 -> bf16 MFMA B-fragment layout
// w3f[t*8+j], t = (o<<11)|(ks<<9)|(ct<<6)|lane :
//   value = bf16(w3[o][c][n]), c = ks*32 + (lane>>4)*8 + j, n = ct*16 + (lane&15)
__global__ __launch_bounds__(256) void w3pack_kernel(const float* __restrict__ w3,
                                                     ushort* __restrict__ w3f) {
    int t = blockIdx.x * 256 + threadIdx.x;   // 27*2048 = 55296 threads exactly
    int lane = t & 63;
    int ct   = (t >> 6) & 7;
    int ks   = (t >> 9) & 3;
    int o    = t >> 11;
    int quad = lane >> 4, l15 = lane & 15;
    int n = ct*16 + l15;
    const float* src = w3 + o*16384;
    ushort out8[8];
#pragma unroll
    for (int j = 0; j < 8; ++j) {
        int c = ks*32 + quad*8 + j;
        float v = src[c*128 + n];
        __hip_bfloat16 bv = __float2bfloat16(v);
        ushort u; __builtin_memcpy(&u, &bv, 2);
        out8[j] = u;
    }
    *(uint4*)&w3f[t*8] = *(uint4*)out8;
}

// ---------------------------------------------------------------- kNN via radius-2 window
__global__ __launch_bounds__(256) void knn_window_kernel(const int* __restrict__ table,
                                                         const int* __restrict__ keyb,
                                                         int* __restrict__ nbr,
                                                         int* __restrict__ flagcnt,
                                                         int* __restrict__ flaglist) {
    __shared__ int okey_sh[125], d2_sh[125];
    __shared__ int tops[256 * 8];
    int tid = threadIdx.x;
    if (tid < 125) {
        int dx = tid / 25 - 2, rr = tid % 25, dy = rr / 5 - 2, dz = rr % 5 - 2;
        okey_sh[tid] = dx * 4096 + dy * 64 + dz;
        d2_sh[tid]   = dx*dx + dy*dy + dz*dz;
    }
    __syncthreads();

    int q   = blockIdx.x * 64 + (tid >> 2);
    int sub = tid & 3;
    int kb  = keyb[q];

    int top[8];
#pragma unroll
    for (int k = 0; k < 8; ++k) top[k] = 0x7FFFFFFF;

    int base = sub * 32;
    int cnt  = (sub == 3) ? 29 : 32;
    for (int i = 0; i < cnt; ++i) {
        int idx = base + i;
        int j = table[kb + okey_sh[idx]];
        if (j >= 0) {
            int key = (d2_sh[idx] << 13) | (j & 8191);
            if (key < top[7]) {
#pragma unroll
                for (int k = 7; k >= 1; --k)
                    top[k] = (key < top[k]) ? max(key, top[k-1]) : top[k];
                top[0] = min(key, top[0]);
            }
        }
    }
#pragma unroll
    for (int k = 0; k < 8; ++k) tops[tid*8 + k] = top[k];
    __syncthreads();

    if (sub == 0) {
        const int* L = &tops[tid*8];
        int ia0 = 0, ia1 = 0, ia2 = 0, ia3 = 0;
        int res[8];
#pragma unroll
        for (int k = 0; k < 8; ++k) {
            int v0 = L[ia0], v1 = L[8 + ia1], v2 = L[16 + ia2], v3 = L[24 + ia3];
            int m01 = min(v0, v1), m23 = min(v2, v3);
            int m = min(m01, m23);
            res[k] = m;
            if (m == v0) ++ia0; else if (m == v1) ++ia1;
            else if (m == v2) ++ia2; else ++ia3;
        }
        int bb = q & ~(M_-1);
        if ((res[7] >> 13) <= 8) {
#pragma unroll
            for (int k = 0; k < 8; ++k) nbr[q*8 + k] = bb + (res[k] & 8191);
        } else {
            int pos = atomicAdd(flagcnt, 1);
            flaglist[pos] = q;
        }
    }
}

// ---------------------------------------------------------------- brute-force cleanup
__global__ __launch_bounds__(256) void knn_bf_kernel(const int* __restrict__ packed,
                                                     const int* __restrict__ flagcnt,
                                                     const int* __restrict__ flaglist,
                                                     int* __restrict__ nbr) {
    __shared__ int tops[256 * 8];
    int tid = threadIdx.x;
    int cnt = *flagcnt;
    for (int f = blockIdx.x; f < cnt; f += gridDim.x) {
        int n = flaglist[f];
        int bb = n & ~(M_-1);
        int p = packed[n];
        int qx = (p >> 10) & 31, qy = (p >> 5) & 31, qz = p & 31;
        int top[8];
#pragma unroll
        for (int k = 0; k < 8; ++k) top[k] = 0x7FFFFFFF;
        for (int j = tid; j < M_; j += 256) {
            int c = packed[bb + j];
            int dx = qx - ((c >> 10) & 31);
            int dy = qy - ((c >> 5) & 31);
            int dz = qz - (c & 31);
            int d2 = dx*dx + dy*dy + dz*dz;
            int key = (d2 << 13) | j;
            if (key < top[7]) {
#pragma unroll
                for (int k = 7; k >= 1; --k)
                    top[k] = (key < top[k]) ? max(key, top[k-1]) : top[k];
                top[0] = min(key, top[0]);
            }
        }
#pragma unroll
        for (int k = 0; k < 8; ++k) tops[tid*8 + k] = top[k];
        __syncthreads();
        for (int stride = 128; stride >= 1; stride >>= 1) {
            if (tid < stride) {
                int* A  = &tops[tid*8];
                int* Bp = &tops[(tid+stride)*8];
                int r[8]; int ia = 0, ib = 0;
#pragma unroll
                for (int k = 0; k < 8; ++k) {
                    int a = A[ia], b2 = Bp[ib];
                    if (a <= b2) { r[k] = a; ++ia; } else { r[k] = b2; ++ib; }
                }
#pragma unroll
                for (int k = 0; k < 8; ++k) A[k] = r[k];
            }
            __syncthreads();
        }
        if (tid == 0) {
#pragma unroll
            for (int k = 0; k < 8; ++k) nbr[n*8 + k] = bb + (tops[k] & 8191);
        }
        __syncthreads();
    }
}

// ---------------------------------------------------------------- 1x1 conv (combined @ w1)
__global__ __launch_bounds__(256) void h1_kernel(const float* __restrict__ feats,
                                                 const int* __restrict__ nbr,
                                                 const float* __restrict__ w1,
                                                 float* __restrict__ hpre) {
    __shared__ float comb[16][72];
    int tid = threadIdx.x;
    int rowbase = blockIdx.x * 16;
    if (tid < 144) {
        int r = tid / 9, s = tid % 9;
        int grow = rowbase + r;
        int idx = (s == 0) ? grow : nbr[grow*8 + (s-1)];
        const float4* f = (const float4*)(feats + idx * 8);
        float4 a = f[0], b = f[1];
        float* dp = &comb[r][s*8];
        dp[0]=a.x; dp[1]=a.y; dp[2]=a.z; dp[3]=a.w;
        dp[4]=b.x; dp[5]=b.y; dp[6]=b.z; dp[7]=b.w;
    }
    __syncthreads();
    int c = tid & 127, rh = tid >> 7;
    float acc[8];
#pragma unroll
    for (int i = 0; i < 8; ++i) acc[i] = 0.f;
    for (int s = 0; s < 72; ++s) {
        float w = w1[s*128 + c];
#pragma unroll
        for (int i = 0; i < 8; ++i)
            acc[i] += comb[rh*8 + i][s] * w;
    }
#pragma unroll
    for (int i = 0; i < 8; ++i)
        hpre[(rowbase + rh*8 + i)*128 + c] = acc[i];
}

// ---------------------------------------------------------------- BN stats (h1 path)
__global__ __launch_bounds__(256) void reduce_kernel(const float* __restrict__ src,
                                                     float* __restrict__ part) {
    __shared__ float ssum[256], ssq[256];
    int tid = threadIdx.x;
    int c = tid & 127, halfr = tid >> 7;
    int rowbase = blockIdx.x * 128 + halfr * 64;
    float s = 0.f, q = 0.f;
    for (int i = 0; i < 64; ++i) {
        float v = src[(rowbase + i)*128 + c];
        s += v; q += v*v;
    }
    ssum[tid] = s; ssq[tid] = q;
    __syncthreads();
    if (tid < 128) {
        part[blockIdx.x*256 + tid]       = ssum[tid] + ssum[tid+128];
        part[blockIdx.x*256 + 128 + tid] = ssq[tid]  + ssq[tid+128];
    }
}

__global__ __launch_bounds__(128) void stats_kernel(const float* __restrict__ part,
                                                    const float* __restrict__ g,
                                                    const float* __restrict__ bias,
                                                    float* __restrict__ scale,
                                                    float* __restrict__ shift) {
    int c = threadIdx.x;
    float s = 0.f, q = 0.f;
    for (int b = 0; b < 256; ++b) {
        s += part[b*256 + c];
        q += part[b*256 + 128 + c];
    }
    float mu  = s / (float)N_;
    float var = q / (float)N_ - mu*mu;
    float inv = rsqrtf(var + EPS_);
    float sc  = inv * g[c];
    scale[c] = sc;
    shift[c] = bias[c] - mu * sc;
}

// BN2 stats from direct sums (conv3 epilogue accumulates gsum)
__global__ __launch_bounds__(128) void stats2_kernel(const float* __restrict__ gsum,
                                                     const float* __restrict__ g,
                                                     const float* __restrict__ bias,
                                                     float* __restrict__ scale,
                                                     float* __restrict__ shift) {
    int c = threadIdx.x;
    float s = gsum[c], q = gsum[128 + c];
    float mu  = s / (float)N_;
    float var = q / (float)N_ - mu*mu;
    float inv = rsqrtf(var + EPS_);
    float sc  = inv * g[c];
    scale[c] = sc;
    shift[c] = bias[c] - mu * sc;
}

// BN+ReLU -> bf16 output (for conv3 A operand)
__global__ __launch_bounds__(256) void bnrelu_bf16_kernel(const float* __restrict__ x,
                                                          const float* __restrict__ scale,
                                                          const float* __restrict__ shift,
                                                          ushort* __restrict__ y) {
    int i = blockIdx.x * 256 + threadIdx.x;
    float4 v = ((const float4*)x)[i];
    int c = (i * 4) & 127;
    v.x = fmaxf(0.f, v.x*scale[c]   + shift[c]);
    v.y = fmaxf(0.f, v.y*scale[c+1] + shift[c+1]);
    v.z = fmaxf(0.f, v.z*scale[c+2] + shift[c+2]);
    v.w = fmaxf(0.f, v.w*scale[c+3] + shift[c+3]);
    ushort o[4];
#pragma unroll
    for (int k = 0; k < 4; ++k) {
        float f = (&v.x)[k];
        __hip_bfloat16 bv = __float2bfloat16(f);
        __builtin_memcpy(&o[k], &bv, 2);
    }
    ((ushort4*)y)[i] = make_ushort4(o[0], o[1], o[2], o[3]);
}

// ---------------------------------------------------------------- 3^3 sparse conv: bf16 MFMA gather-GEMM
// R7 = R6 data paths (verified correct) with A-prefetch FORCED via asm volatile
// global_load_dwordx4 into alternating named register arrays (aA/aB). The
// compiler cannot sink asm, so A(o+1) issues right after the barrier and has the
// whole compute(o) phase to land. Per-iter sync: s_waitcnt vmcnt(0)+s_barrier
// (only last iter's 12 loads outstanding) + sched_barrier(0) (rule #18).
// LDS/iter: B 32K write + 128K read (was 256K in R3/R4). A never touches LDS.
#define CONV3_LDS 79872
#define GLL(src, dst) __builtin_amdgcn_global_load_lds( \
    (const __attribute__((address_space(1))) unsigned int*)(src), \
    (__attribute__((address_space(3))) unsigned int*)(dst), 16, 0, 0)

__device__ __forceinline__ int okey_of(int o) {
    int dx = o/9 - 1, dy = (o/3)%3 - 1, dz = o%3 - 1;
    return dx*4096 + dy*64 + dz;
}

// 8 forced A-loads: NXT[2*ks+i] = hb[j_i*128 + quad*8 + ks*32], 16B each
#define A_LOAD(NXT, on) { \
    int jn0 = jsh[(on)*128 + row0], jn1 = jsh[(on)*128 + row1]; \
    const ushort* p0 = hb + (long)jn0*128 + quad*8; \
    const ushort* p1 = hb + (long)jn1*128 + quad*8; \
    asm volatile("global_load_dwordx4 %0, %2, off\n\t" \
                 "global_load_dwordx4 %1, %3, off" \
                 : "=&v"(NXT[0]), "=&v"(NXT[1]) : "v"(p0), "v"(p1)); \
    asm volatile("global_load_dwordx4 %0, %2, off offset:64\n\t" \
                 "global_load_dwordx4 %1, %3, off offset:64" \
                 : "=&v"(NXT[2]), "=&v"(NXT[3]) : "v"(p0), "v"(p1)); \
    asm volatile("global_load_dwordx4 %0, %2, off offset:128\n\t" \
                 "global_load_dwordx4 %1, %3, off offset:128" \
                 : "=&v"(NXT[4]), "=&v"(NXT[5]) : "v"(p0), "v"(p1)); \
    asm volatile("global_load_dwordx4 %0, %2, off offset:192\n\t" \
                 "global_load_dwordx4 %1, %3, off offset:192" \
                 : "=&v"(NXT[6]), "=&v"(NXT[7]) : "v"(p0), "v"(p1)); \
}

// one pipeline step: wait+barrier; issue A(o+1)->NXT, B(o+1)->other slot; compute(o) on CUR
#define STEP(o_, CUR, NXT) { \
    asm volatile("s_waitcnt vmcnt(0)\n\ts_barrier" ::: "memory"); \
    __builtin_amdgcn_sched_barrier(0); \
    int on = ((o_)+1 < 27) ? (o_)+1 : 26; \
    A_LOAD(NXT, on); \
    { const ushort* wsrc = w3f + (on << 14); \
      char* bdst = smem_raw + ((((o_)+1) & 1) << 15); \
      for (int i = 0; i < 4; ++i) { int flat = i*512 + tid; GLL(wsrc + flat*8, bdst + (flat << 4)); } } \
    const ushort* Bc = (const ushort*)(smem_raw + (((o_) & 1) << 15)); \
    for (int ks = 0; ks < 4; ++ks) { \
        short8 bfr0 = *(const short8*)&Bc[((ks*8 + cb + 0)*64 + lane) << 3]; \
        short8 bfr1 = *(const short8*)&Bc[((ks*8 + cb + 1)*64 + lane) << 3]; \
        short8 bfr2 = *(const short8*)&Bc[((ks*8 + cb + 2)*64 + lane) << 3]; \
        short8 bfr3 = *(const short8*)&Bc[((ks*8 + cb + 3)*64 + lane) << 3]; \
        acc[0][0] = __builtin_amdgcn_mfma_f32_16x16x32_bf16(CUR[ks*2+0], bfr0, acc[0][0], 0, 0, 0); \
        acc[1][0] = __builtin_amdgcn_mfma_f32_16x16x32_bf16(CUR[ks*2+1], bfr0, acc[1][0], 0, 0, 0); \
        acc[0][1] = __builtin_amdgcn_mfma_f32_16x16x32_bf16(CUR[ks*2+0], bfr1, acc[0][1], 0, 0, 0); \
        acc[1][1] = __builtin_amdgcn_mfma_f32_16x16x32_bf16(CUR[ks*2+1], bfr1, acc[1][1], 0, 0, 0); \
        acc[0][2] = __builtin_amdgcn_mfma_f32_16x16x32_bf16(CUR[ks*2+0], bfr2, acc[0][2], 0, 0, 0); \
        acc[1][2] = __builtin_amdgcn_mfma_f32_16x16x32_bf16(CUR[ks*2+1], bfr2, acc[1][2], 0, 0, 0); \
        acc[0][3] = __builtin_amdgcn_mfma_f32_16x16x32_bf16(CUR[ks*2+0], bfr3, acc[0][3], 0, 0, 0); \
        acc[1][3] = __builtin_amdgcn_mfma_f32_16x16x32_bf16(CUR[ks*2+1], bfr3, acc[1][3], 0, 0, 0); \
    } }

__global__ __launch_bounds__(512) void conv3_mfma_kernel(const ushort* __restrict__ hb,
                                                         const ushort* __restrict__ w3f,
                                                         const int* __restrict__ table,
                                                         const int* __restrict__ keyb,
                                                         float* __restrict__ h2,
                                                         float* __restrict__ gsum) {
    extern __shared__ char smem_raw[];
    // B ring: 2 x 32768 B at offset 0 ; jsh: 27*128*4 = 13824 B at 65536
    int* jsh = (int*)(smem_raw + 65536);
    int tid = threadIdx.x;
    int lane = tid & 63, wid = tid >> 6;
    int quad = lane >> 4, l15 = lane & 15;
    int bid = blockIdx.x;
    int swz = (bid & 7) * 32 + (bid >> 3);   // XCD-chunked, bijective (256 % 8 == 0)
    int rowbase = swz * 128;
    int wr = wid >> 1;              // row group 0..3 (32 rows each)
    int cb = (wid & 1) * 4;         // col-tile base (0 or 4)

    // all 27x128 table lookups -> jsh (invalid stays -1 -> zero row at hb - 128)
    for (int t = tid; t < 27*128; t += 512) {
        int o = t >> 7, r = t & 127;
        jsh[t] = table[keyb[rowbase + r] + okey_of(o)];
    }
    __syncthreads();

    int row0 = wr*32 + l15;          // this lane's A rows (tile i=0 / i=1)
    int row1 = row0 + 16;

    // prologue: A(0) -> aA (forced), B(0) -> LDS slot 0
    short8 aA[8], aB[8];
    A_LOAD(aA, 0);
#pragma unroll
    for (int i = 0; i < 4; ++i) {
        int flat = i*512 + tid;
        GLL(w3f + flat*8, smem_raw + (flat << 4));
    }

    f32x4 acc[2][4];
#pragma unroll
    for (int i = 0; i < 2; ++i)
#pragma unroll
        for (int c = 0; c < 4; ++c)
            acc[i][c] = (f32x4){0.f, 0.f, 0.f, 0.f};

#pragma unroll 1
    for (int o = 0; o < 27; o += 2) {
        STEP(o, aA, aB);
        if (o + 1 < 27) STEP(o + 1, aB, aA);
    }
    asm volatile("s_waitcnt vmcnt(0)" ::: "memory");
    __syncthreads();   // full drain before LDS reuse

    // epilogue: store h2 + per-column BN2 partial sums
    float s[4], q[4];
#pragma unroll
    for (int c = 0; c < 4; ++c) { s[c] = 0.f; q[c] = 0.f; }
#pragma unroll
    for (int i = 0; i < 2; ++i)
#pragma unroll
        for (int c = 0; c < 4; ++c)
#pragma unroll
            for (int r = 0; r < 4; ++r) {
                int row = rowbase + wr*32 + i*16 + quad*4 + r;
                int col = (cb + c)*16 + l15;
                float v = acc[i][c][r];
                h2[row*128 + col] = v;
                s[c] += v; q[c] += v*v;
            }
    float* red = (float*)smem_raw;   // 256 floats: sums[128] | sqs[128]
    if (tid < 256) red[tid] = 0.f;
    __syncthreads();
#pragma unroll
    for (int c = 0; c < 4; ++c) {
        int col = (cb + c)*16 + l15;
        atomicAdd(&red[col], s[c]);
        atomicAdd(&red[128 + col], q[c]);
    }
    __syncthreads();
    if (tid < 256) atomicAdd(&gsum[tid], red[tid]);
}

// ---------------------------------------------------------------- final 1x1 conv, fused BN2+ReLU
// Stage BN'd rows in padded LDS (stride 129: conflict-free) + wout in LDS;
// float4 w-reads. Replaces ~134M scalar global loads (16x row duplication).
__global__ __launch_bounds__(256) void out_kernel(const float* __restrict__ h2,
                                                  const float* __restrict__ wout,
                                                  const float* __restrict__ scale,
                                                  const float* __restrict__ shift,
                                                  float* __restrict__ out) {
    __shared__ float hrow[128][129];
    __shared__ float wsh[2048];
    __shared__ float sc[128], sh[128];
    int tid = threadIdx.x;
    if (tid < 128) { sc[tid] = scale[tid]; sh[tid] = shift[tid]; }
#pragma unroll
    for (int i = 0; i < 8; ++i) wsh[i*256 + tid] = wout[i*256 + tid];
    __syncthreads();

    int rowbase = blockIdx.x * 128;
    // stage 128 rows, applying BN+ReLU once per element
#pragma unroll
    for (int i = 0; i < 16; ++i) {
        int flat = i*256 + tid;              // 4096 float4 chunks
        int row = flat >> 5, c4 = (flat & 31) * 4;
        float4 v = *(const float4*)&h2[(rowbase + row)*128 + c4];
        float4 scv = *(const float4*)&sc[c4];
        float4 shv = *(const float4*)&sh[c4];
        hrow[row][c4+0] = fmaxf(0.f, fmaf(v.x, scv.x, shv.x));
        hrow[row][c4+1] = fmaxf(0.f, fmaf(v.y, scv.y, shv.y));
        hrow[row][c4+2] = fmaxf(0.f, fmaf(v.z, scv.z, shv.z));
        hrow[row][c4+3] = fmaxf(0.f, fmaf(v.w, scv.w, shv.w));
    }
    __syncthreads();

    int row = tid >> 1, dbase = (tid & 1) * 8;
    float acc[8];
#pragma unroll
    for (int k = 0; k < 8; ++k) acc[k] = 0.f;
    for (int c = 0; c < 128; ++c) {
        float hv = hrow[row][c];
        float4 w0 = *(const float4*)&wsh[c*16 + dbase];
        float4 w1 = *(const float4*)&wsh[c*16 + dbase + 4];
        acc[0] = fmaf(hv, w0.x, acc[0]);
        acc[1] = fmaf(hv, w0.y, acc[1]);
        acc[2] = fmaf(hv, w0.z, acc[2]);
        acc[3] = fmaf(hv, w0.w, acc[3]);
        acc[4] = fmaf(hv, w1.x, acc[4]);
        acc[5] = fmaf(hv, w1.y, acc[5]);
        acc[6] = fmaf(hv, w1.z, acc[6]);
        acc[7] = fmaf(hv, w1.w, acc[7]);
    }
    float* op = out + (rowbase + row)*16 + dbase;
    *(float4*)op       = (float4){acc[0], acc[1], acc[2], acc[3]};
    *(float4*)(op + 4) = (float4){acc[4], acc[5], acc[6], acc[7]};
}

// ---------------------------------------------------------------- launch
extern "C" void kernel_launch(void* const* d_in, const int* in_sizes, int n_in,
                              void* d_out, int out_size, void* d_ws, size_t ws_size,
                              hipStream_t stream) {
    const int*   coords = (const int*)d_in[0];
    const float* feats  = (const float*)d_in[1];
    const float* w1     = (const float*)d_in[2];
    const float* g1     = (const float*)d_in[3];
    const float* b1     = (const float*)d_in[4];
    const float* w3     = (const float*)d_in[5];
    const float* g2     = (const float*)d_in[6];
    const float* b2     = (const float*)d_in[7];
    const float* wout   = (const float*)d_in[8];
    float* out = (float*)d_out;

    char* ws = (char*)d_ws;
    int*    table_base = (int*)(ws);                              // 4.03 MB
    int*    table   = table_base + GUARD;
    int*    packed  = (int*)(ws + (4352u<<10));                   // 128 KB
    int*    keyb    = (int*)(ws + (4608u<<10));                   // 128 KB
    int*    nbr     = (int*)(ws + (4864u<<10));                   // 1 MB
    int*    flagcnt = (int*)(ws + (5888u<<10));                   // 4 B
    int*    flaglist= (int*)(ws + (5892u<<10));                   // 128 KB
    float*  part    = (float*)(ws + (6144u<<10));                 // 256 KB (BN1 partials)
    float*  scale1  = (float*)(ws + (6400u<<10));
    float*  shift1  = scale1 + 128;
    float*  scale2  = shift1 + 128;
    float*  shift2  = scale2 + 128;
    float*  gsum    = (float*)(ws + (6416u<<10));                 // 1 KB (BN2 direct sums)
    ushort* w3f     = (ushort*)(ws + (6656u<<10));                // 0.88 MB (ends 7520K)
    ushort* hb      = (ushort*)(ws + (7680u<<10));                // 8 MB; hb-128 = 256B zero row
    float*  h       = (float*)(ws + (15872u<<10));                // 16 MB
    float*  h2      = h;   // aliased: h is dead once hb is written, conv3 reads only hb

    static bool conv3_attr_set = false;
    if (!conv3_attr_set) {
        hipFuncSetAttribute(reinterpret_cast<const void*>(&conv3_mfma_kernel),
                            hipFuncAttributeMaxDynamicSharedMemorySize, CONV3_LDS);
        conv3_attr_set = true;
    }

    hipMemsetAsync(table_base, 0xFF, (TBL + GUARD) * sizeof(int), stream);
    hipMemsetAsync(flagcnt, 0, sizeof(int), stream);
    prep_kernel      <<<N_/256, 256, 0, stream>>>(coords, table, packed, keyb,
                                                  gsum, (unsigned int*)(hb - 128));
    w3pack_kernel    <<<216, 256, 0, stream>>>(w3, w3f);
    knn_window_kernel<<<N_/64, 256, 0, stream>>>(table, keyb, nbr, flagcnt, flaglist);
    knn_bf_kernel    <<<256, 256, 0, stream>>>(packed, flagcnt, flaglist, nbr);
    h1_kernel        <<<N_/16, 256, 0, stream>>>(feats, nbr, w1, h);
    reduce_kernel    <<<N_/128, 256, 0, stream>>>(h, part);
    stats_kernel     <<<1, 128, 0, stream>>>(part, g1, b1, scale1, shift1);
    bnrelu_bf16_kernel<<<(N_*H_/4)/256, 256, 0, stream>>>(h, scale1, shift1, hb);
    conv3_mfma_kernel<<<N_/128, 512, CONV3_LDS, stream>>>(hb, w3f, table, keyb, h2, gsum);
    stats2_kernel    <<<1, 128, 0, stream>>>(gsum, g2, b2, scale2, shift2);
    out_kernel       <<<N_/128, 256, 0, stream>>>(h2, wout, scale2, shift2, out);
}

// Round 8
// 194.349 us; speedup vs baseline: 1.2124x; 1.1690x over previous
//
#include <hip/hip_runtime.h>
#include <hip/hip_bf16.h>

#define B_   4
#define M_   8192
#define N_   32768
#define H_   128
#define EPS_ 1e-5f
#define TBL  1048576   // 4 * 64^3 dense hash table
#define GUARD 8192     // negative-offset guard for window probes

typedef short short8 __attribute__((ext_vector_type(8)));   // 8 bf16 (4 VGPRs)
typedef float f32x4  __attribute__((ext_vector_type(4)));   // 4 fp32 acc

// ---------------------------------------------------------------- fused prep + w3pack + zero-init
// blocks 0..127: prep (coords -> table/packed/keyb); blocks 0..7 also zero gsum1
// replicas; block 0 zeros gsum2; block 8 zeros the hb zero-row; block 9 zeros flagcnt.
// blocks 128..343: w3pack (w3 -> bf16 MFMA B-fragment layout)
// w3f[t*8+j], t = (o<<11)|(ks<<9)|(ct<<6)|lane :
//   value = bf16(w3[o][c][n]), c = ks*32 + (lane>>4)*8 + j, n = ct*16 + (lane&15)
__global__ __launch_bounds__(256) void prep_pack_kernel(const int* __restrict__ coords,
                                                        int* __restrict__ table,
                                                        int* __restrict__ packed,
                                                        int* __restrict__ keyb,
                                                        const float* __restrict__ w3,
                                                        ushort* __restrict__ w3f,
                                                        float* __restrict__ gsum1,
                                                        float* __restrict__ gsum2,
                                                        int* __restrict__ flagcnt,
                                                        unsigned int* __restrict__ hbz) {
    int bid = blockIdx.x, tid = threadIdx.x;
    if (bid < 128) {
        int n = bid * 256 + tid;
        int b = coords[4*n+0], x = coords[4*n+1], y = coords[4*n+2], z = coords[4*n+3];
        packed[n] = (x << 10) | (y << 5) | z;
        int key = ((b*64 + x+1)*64 + y+1)*64 + (z+1);
        keyb[n] = key;
        table[key] = n;
        if (bid < 8)  gsum1[bid*256 + tid] = 0.f;    // 8 replicas x 256
        if (bid == 0) gsum2[tid] = 0.f;              // 256
        if (bid == 8 && tid < 64) hbz[tid] = 0u;     // 256B zero row
        if (bid == 9 && tid == 0) *flagcnt = 0;
        return;
    }
    int t = (bid - 128) * 256 + tid;   // 27*2048 = 55296 threads exactly
    int lane = t & 63;
    int ct   = (t >> 6) & 7;
    int ks   = (t >> 9) & 3;
    int o    = t >> 11;
    int quad = lane >> 4, l15 = lane & 15;
    int n = ct*16 + l15;
    const float* src = w3 + o*16384;
    ushort out8[8];
#pragma unroll
    for (int j = 0; j < 8; ++j) {
        int c = ks*32 + quad*8 + j;
        float v = src[c*128 + n];
        __hip_bfloat16 bv = __float2bfloat16(v);
        ushort u; __builtin_memcpy(&u, &bv, 2);
        out8[j] = u;
    }
    *(uint4*)&w3f[t*8] = *(uint4*)out8;
}

// ---------------------------------------------------------------- kNN via radius-2 window
// Only the 93 cells with d2<=8 are probed: cells with d2>8 can never appear in an
// ACCEPTED top-8 (acceptance requires 8th d2<=8), and queries with <8 candidates
// at d2<=8 flag to brute-force either way -> output provably identical to 125-cell.
__global__ __launch_bounds__(256) void knn_window_kernel(const int* __restrict__ table,
                                                         const int* __restrict__ keyb,
                                                         int* __restrict__ nbr,
                                                         int* __restrict__ flagcnt,
                                                         int* __restrict__ flaglist) {
    __shared__ int okey_sh[93], d2_sh[93];
    __shared__ int tops[256 * 8];
    __shared__ int ncnt;
    int tid = threadIdx.x;
    if (tid == 0) ncnt = 0;
    __syncthreads();
    if (tid < 125) {
        int dx = tid / 25 - 2, rr = tid % 25, dy = rr / 5 - 2, dz = rr % 5 - 2;
        int d2 = dx*dx + dy*dy + dz*dz;
        if (d2 <= 8) {
            int p = atomicAdd(&ncnt, 1);
            okey_sh[p] = dx * 4096 + dy * 64 + dz;
            d2_sh[p]   = d2;
        }
    }
    __syncthreads();

    int q   = blockIdx.x * 64 + (tid >> 2);
    int sub = tid & 3;
    int kb  = keyb[q];

    int top[8];
#pragma unroll
    for (int k = 0; k < 8; ++k) top[k] = 0x7FFFFFFF;

    int base = sub * 24;
    int cnt  = (sub == 3) ? 21 : 24;   // 93 = 24+24+24+21
    for (int i = 0; i < cnt; ++i) {
        int idx = base + i;
        int j = table[kb + okey_sh[idx]];
        if (j >= 0) {
            int key = (d2_sh[idx] << 13) | (j & 8191);
            if (key < top[7]) {
#pragma unroll
                for (int k = 7; k >= 1; --k)
                    top[k] = (key < top[k]) ? max(key, top[k-1]) : top[k];
                top[0] = min(key, top[0]);
            }
        }
    }
#pragma unroll
    for (int k = 0; k < 8; ++k) tops[tid*8 + k] = top[k];
    __syncthreads();

    if (sub == 0) {
        const int* L = &tops[tid*8];
        int ia0 = 0, ia1 = 0, ia2 = 0, ia3 = 0;
        int res[8];
#pragma unroll
        for (int k = 0; k < 8; ++k) {
            int v0 = L[ia0], v1 = L[8 + ia1], v2 = L[16 + ia2], v3 = L[24 + ia3];
            int m01 = min(v0, v1), m23 = min(v2, v3);
            int m = min(m01, m23);
            res[k] = m;
            if (m == v0) ++ia0; else if (m == v1) ++ia1;
            else if (m == v2) ++ia2; else ++ia3;
        }
        int bb = q & ~(M_-1);
        if ((res[7] >> 13) <= 8) {
#pragma unroll
            for (int k = 0; k < 8; ++k) nbr[q*8 + k] = bb + (res[k] & 8191);
        } else {
            int pos = atomicAdd(flagcnt, 1);
            flaglist[pos] = q;
        }
    }
}

// ---------------------------------------------------------------- brute-force cleanup
__global__ __launch_bounds__(256) void knn_bf_kernel(const int* __restrict__ packed,
                                                     const int* __restrict__ flagcnt,
                                                     const int* __restrict__ flaglist,
                                                     int* __restrict__ nbr) {
    __shared__ int tops[256 * 8];
    int tid = threadIdx.x;
    int cnt = *flagcnt;
    for (int f = blockIdx.x; f < cnt; f += gridDim.x) {
        int n = flaglist[f];
        int bb = n & ~(M_-1);
        int p = packed[n];
        int qx = (p >> 10) & 31, qy = (p >> 5) & 31, qz = p & 31;
        int top[8];
#pragma unroll
        for (int k = 0; k < 8; ++k) top[k] = 0x7FFFFFFF;
        for (int j = tid; j < M_; j += 256) {
            int c = packed[bb + j];
            int dx = qx - ((c >> 10) & 31);
            int dy = qy - ((c >> 5) & 31);
            int dz = qz - (c & 31);
            int d2 = dx*dx + dy*dy + dz*dz;
            int key = (d2 << 13) | j;
            if (key < top[7]) {
#pragma unroll
                for (int k = 7; k >= 1; --k)
                    top[k] = (key < top[k]) ? max(key, top[k-1]) : top[k];
                top[0] = min(key, top[0]);
            }
        }
#pragma unroll
        for (int k = 0; k < 8; ++k) tops[tid*8 + k] = top[k];
        __syncthreads();
        for (int stride = 128; stride >= 1; stride >>= 1) {
            if (tid < stride) {
                int* A  = &tops[tid*8];
                int* Bp = &tops[(tid+stride)*8];
                int r[8]; int ia = 0, ib = 0;
#pragma unroll
                for (int k = 0; k < 8; ++k) {
                    int a = A[ia], b2 = Bp[ib];
                    if (a <= b2) { r[k] = a; ++ia; } else { r[k] = b2; ++ib; }
                }
#pragma unroll
                for (int k = 0; k < 8; ++k) A[k] = r[k];
            }
            __syncthreads();
        }
        if (tid == 0) {
#pragma unroll
            for (int k = 0; k < 8; ++k) nbr[n*8 + k] = bb + (tops[k] & 8191);
        }
        __syncthreads();
    }
}

// ---------------------------------------------------------------- 1x1 conv (combined @ w1) + BN1 partial sums
// Epilogue reduces the block's 16x128 output to per-column sum/sumsq in LDS and
// atomicAdds into one of 8 gsum1 replicas (caps per-address contention at 256).
__global__ __launch_bounds__(256) void h1_kernel(const float* __restrict__ feats,
                                                 const int* __restrict__ nbr,
                                                 const float* __restrict__ w1,
                                                 float* __restrict__ hpre,
                                                 float* __restrict__ gsum1) {
    __shared__ float comb[16][72];
    __shared__ float ssum[256], ssq[256];
    int tid = threadIdx.x;
    int rowbase = blockIdx.x * 16;
    if (tid < 144) {
        int r = tid / 9, s = tid % 9;
        int grow = rowbase + r;
        int idx = (s == 0) ? grow : nbr[grow*8 + (s-1)];
        const float4* f = (const float4*)(feats + idx * 8);
        float4 a = f[0], b = f[1];
        float* dp = &comb[r][s*8];
        dp[0]=a.x; dp[1]=a.y; dp[2]=a.z; dp[3]=a.w;
        dp[4]=b.x; dp[5]=b.y; dp[6]=b.z; dp[7]=b.w;
    }
    __syncthreads();
    int c = tid & 127, rh = tid >> 7;
    float acc[8];
#pragma unroll
    for (int i = 0; i < 8; ++i) acc[i] = 0.f;
    for (int s = 0; s < 72; ++s) {
        float w = w1[s*128 + c];
#pragma unroll
        for (int i = 0; i < 8; ++i)
            acc[i] += comb[rh*8 + i][s] * w;
    }
    float s = 0.f, q = 0.f;
#pragma unroll
    for (int i = 0; i < 8; ++i) {
        hpre[(rowbase + rh*8 + i)*128 + c] = acc[i];
        s += acc[i]; q += acc[i]*acc[i];
    }
    ssum[tid] = s; ssq[tid] = q;
    __syncthreads();
    if (tid < 128) {
        float S = ssum[tid] + ssum[tid+128];
        float Q = ssq[tid]  + ssq[tid+128];
        float* g = gsum1 + (blockIdx.x & 7) * 256;
        atomicAdd(&g[tid], S);
        atomicAdd(&g[128 + tid], Q);
    }
}

// ---------------------------------------------------------------- BN1+ReLU -> bf16 (inline stats from gsum1)
__global__ __launch_bounds__(256) void bnrelu_bf16_kernel(const float* __restrict__ x,
                                                          const float* __restrict__ gsum1,
                                                          const float* __restrict__ g1,
                                                          const float* __restrict__ b1,
                                                          ushort* __restrict__ y) {
    __shared__ float sc[128], sh[128];
    int tid = threadIdx.x;
    if (tid < 128) {
        float s = 0.f, q = 0.f;
#pragma unroll
        for (int r = 0; r < 8; ++r) {
            s += gsum1[r*256 + tid];
            q += gsum1[r*256 + 128 + tid];
        }
        float mu  = s / (float)N_;
        float var = q / (float)N_ - mu*mu;
        float inv = rsqrtf(var + EPS_);
        float scv = inv * g1[tid];
        sc[tid] = scv;
        sh[tid] = b1[tid] - mu * scv;
    }
    __syncthreads();
    int i = blockIdx.x * 256 + tid;
    float4 v = ((const float4*)x)[i];
    int c = (i * 4) & 127;
    v.x = fmaxf(0.f, v.x*sc[c]   + sh[c]);
    v.y = fmaxf(0.f, v.y*sc[c+1] + sh[c+1]);
    v.z = fmaxf(0.f, v.z*sc[c+2] + sh[c+2]);
    v.w = fmaxf(0.f, v.w*sc[c+3] + sh[c+3]);
    ushort o[4];
#pragma unroll
    for (int k = 0; k < 4; ++k) {
        float f = (&v.x)[k];
        __hip_bfloat16 bv = __float2bfloat16(f);
        __builtin_memcpy(&o[k], &bv, 2);
    }
    ((ushort4*)y)[i] = make_ushort4(o[0], o[1], o[2], o[3]);
}

// ---------------------------------------------------------------- 3^3 sparse conv: pipelined bf16 MFMA gather-GEMM
// R3 structure (best measured: 50.4 us): 128x128 block, 8 waves, A+B double-
// buffered in LDS via global_load_lds, one __syncthreads per offset.
#define CONV3_LDS 145408
__global__ __launch_bounds__(512) void conv3_mfma_kernel(const ushort* __restrict__ hb,
                                                         const ushort* __restrict__ w3f,
                                                         const int* __restrict__ table,
                                                         const int* __restrict__ keyb,
                                                         float* __restrict__ h2,
                                                         float* __restrict__ gsum) {
    extern __shared__ char smem_raw[];
    ushort* Asb = (ushort*)smem_raw;                 // 2 x 32768 B  [buf][row 0..127][chunk^(row&15)]
    ushort* Bsb = (ushort*)(smem_raw + 65536);       // 2 x 32768 B  fragment-major copy of w3f[o]
    int*    jsh = (int*)(smem_raw + 131072);         // 27*128*4 = 13824 B
    int*    kbsh= (int*)(smem_raw + 144896);         // 512 B

    int tid = threadIdx.x;
    int lane = tid & 63, wid = tid >> 6;
    int quad = lane >> 4, l15 = lane & 15;
    int bid = blockIdx.x;
    int swz = (bid & 7) * 32 + (bid >> 3);   // XCD-chunked, bijective (256 % 8 == 0)
    int rowbase = swz * 128;
    int wr = wid >> 1;              // row group 0..3 (32 rows each)
    int cb = (wid & 1) * 4;         // col-tile base (0 or 4)

    if (tid < 128) kbsh[tid] = keyb[rowbase + tid];
    __syncthreads();
    // all 27x128 table lookups up front (invalid stays -1 -> zero row at hb - 128)
    for (int t = tid; t < 27*128; t += 512) {
        int o = t >> 7, r = t & 127;
        int dx = o/9 - 1, dy = (o/3)%3 - 1, dz = o%3 - 1;
        jsh[t] = table[kbsh[r] + dx*4096 + dy*64 + dz];
    }
    __syncthreads();

    // stage A(0) + B(0)
#pragma unroll
    for (int i = 0; i < 4; ++i) {
        int flat = i*512 + tid;             // 2048 chunks of 16B each
        int r = flat >> 4, cp = flat & 15;
        int j = jsh[r];
        const ushort* asrc = hb + j*128 + ((cp ^ (r & 15)) << 3);
        __builtin_amdgcn_global_load_lds(
            (const __attribute__((address_space(1))) unsigned int*)asrc,
            (__attribute__((address_space(3))) unsigned int*)&Asb[flat << 3],
            16, 0, 0);
        __builtin_amdgcn_global_load_lds(
            (const __attribute__((address_space(1))) unsigned int*)(w3f + (flat << 3)),
            (__attribute__((address_space(3))) unsigned int*)&Bsb[flat << 3],
            16, 0, 0);
    }
    __syncthreads();   // drains vmcnt(0): A(0), B(0) resident

    f32x4 acc[2][4];
#pragma unroll
    for (int i = 0; i < 2; ++i)
#pragma unroll
        for (int c = 0; c < 4; ++c)
            acc[i][c] = (f32x4){0.f, 0.f, 0.f, 0.f};

    int cur = 0;
#pragma unroll 1
    for (int o = 0; o < 27; ++o) {
        // stage A(o+1), B(o+1) into the other buffers; complete during MFMAs below
        if (o < 26) {
            int obase = (o + 1) << 7;
            const ushort* wsrc = w3f + ((o + 1) << 14);
            int dst = (cur ^ 1) * 16384;
#pragma unroll
            for (int i = 0; i < 4; ++i) {
                int flat = i*512 + tid;
                int r = flat >> 4, cp = flat & 15;
                int j = jsh[obase + r];
                const ushort* asrc = hb + j*128 + ((cp ^ (r & 15)) << 3);
                __builtin_amdgcn_global_load_lds(
                    (const __attribute__((address_space(1))) unsigned int*)asrc,
                    (__attribute__((address_space(3))) unsigned int*)&Asb[dst + (flat << 3)],
                    16, 0, 0);
                __builtin_amdgcn_global_load_lds(
                    (const __attribute__((address_space(1))) unsigned int*)(wsrc + (flat << 3)),
                    (__attribute__((address_space(3))) unsigned int*)&Bsb[dst + (flat << 3)],
                    16, 0, 0);
            }
        }
        // compute on buffers[cur]: conflict-free ds_read_b128 only
        const ushort* Ac = Asb + cur*16384;
        const ushort* Bc = Bsb + cur*16384;
#pragma unroll
        for (int ks = 0; ks < 4; ++ks) {
            short8 af[2], bfr[4];
#pragma unroll
            for (int i = 0; i < 2; ++i) {
                int lr = wr*32 + i*16 + l15;
                int chunk = (ks*4 + quad) ^ l15;
                af[i] = *(const short8*)&Ac[lr*128 + chunk*8];
            }
#pragma unroll
            for (int c = 0; c < 4; ++c)
                bfr[c] = *(const short8*)&Bc[((ks*8 + cb + c)*64 + lane) << 3];
#pragma unroll
            for (int i = 0; i < 2; ++i)
#pragma unroll
                for (int c = 0; c < 4; ++c)
                    acc[i][c] = __builtin_amdgcn_mfma_f32_16x16x32_bf16(af[i], bfr[c], acc[i][c], 0, 0, 0);
        }
        __syncthreads();   // drains vmcnt(0): next A/B landed; current buffers free
        cur ^= 1;
    }

    // epilogue: store h2 + per-column BN2 partial sums
    float s[4], q[4];
#pragma unroll
    for (int c = 0; c < 4; ++c) { s[c] = 0.f; q[c] = 0.f; }
#pragma unroll
    for (int i = 0; i < 2; ++i)
#pragma unroll
        for (int c = 0; c < 4; ++c)
#pragma unroll
            for (int r = 0; r < 4; ++r) {
                int row = rowbase + wr*32 + i*16 + quad*4 + r;
                int col = (cb + c)*16 + l15;
                float v = acc[i][c][r];
                h2[row*128 + col] = v;
                s[c] += v; q[c] += v*v;
            }
    float* red = (float*)smem_raw;   // 256 floats: sums[128] | sqs[128]
    if (tid < 256) red[tid] = 0.f;
    __syncthreads();
#pragma unroll
    for (int c = 0; c < 4; ++c) {
        int col = (cb + c)*16 + l15;
        atomicAdd(&red[col], s[c]);
        atomicAdd(&red[128 + col], q[c]);
    }
    __syncthreads();
    if (tid < 256) atomicAdd(&gsum[tid], red[tid]);
}

// ---------------------------------------------------------------- final 1x1 conv, fused BN2+ReLU (inline stats)
__global__ __launch_bounds__(256) void out_kernel(const float* __restrict__ h2,
                                                  const float* __restrict__ wout,
                                                  const float* __restrict__ gsum2,
                                                  const float* __restrict__ g2,
                                                  const float* __restrict__ b2,
                                                  float* __restrict__ out) {
    __shared__ float hrow[128][129];
    __shared__ float wsh[2048];
    __shared__ float sc[128], sh[128];
    int tid = threadIdx.x;
    if (tid < 128) {
        float s = gsum2[tid], q = gsum2[128 + tid];
        float mu  = s / (float)N_;
        float var = q / (float)N_ - mu*mu;
        float inv = rsqrtf(var + EPS_);
        float scv = inv * g2[tid];
        sc[tid] = scv;
        sh[tid] = b2[tid] - mu * scv;
    }
#pragma unroll
    for (int i = 0; i < 8; ++i) wsh[i*256 + tid] = wout[i*256 + tid];
    __syncthreads();

    int rowbase = blockIdx.x * 128;
    // stage 128 rows, applying BN+ReLU once per element
#pragma unroll
    for (int i = 0; i < 16; ++i) {
        int flat = i*256 + tid;              // 4096 float4 chunks
        int row = flat >> 5, c4 = (flat & 31) * 4;
        float4 v = *(const float4*)&h2[(rowbase + row)*128 + c4];
        float4 scv = *(const float4*)&sc[c4];
        float4 shv = *(const float4*)&sh[c4];
        hrow[row][c4+0] = fmaxf(0.f, fmaf(v.x, scv.x, shv.x));
        hrow[row][c4+1] = fmaxf(0.f, fmaf(v.y, scv.y, shv.y));
        hrow[row][c4+2] = fmaxf(0.f, fmaf(v.z, scv.z, shv.z));
        hrow[row][c4+3] = fmaxf(0.f, fmaf(v.w, scv.w, shv.w));
    }
    __syncthreads();

    int row = tid >> 1, dbase = (tid & 1) * 8;
    float acc[8];
#pragma unroll
    for (int k = 0; k < 8; ++k) acc[k] = 0.f;
    for (int c = 0; c < 128; ++c) {
        float hv = hrow[row][c];
        float4 w0 = *(const float4*)&wsh[c*16 + dbase];
        float4 w1 = *(const float4*)&wsh[c*16 + dbase + 4];
        acc[0] = fmaf(hv, w0.x, acc[0]);
        acc[1] = fmaf(hv, w0.y, acc[1]);
        acc[2] = fmaf(hv, w0.z, acc[2]);
        acc[3] = fmaf(hv, w0.w, acc[3]);
        acc[4] = fmaf(hv, w1.x, acc[4]);
        acc[5] = fmaf(hv, w1.y, acc[5]);
        acc[6] = fmaf(hv, w1.z, acc[6]);
        acc[7] = fmaf(hv, w1.w, acc[7]);
    }
    float* op = out + (rowbase + row)*16 + dbase;
    *(float4*)op       = (float4){acc[0], acc[1], acc[2], acc[3]};
    *(float4*)(op + 4) = (float4){acc[4], acc[5], acc[6], acc[7]};
}

// ---------------------------------------------------------------- launch
extern "C" void kernel_launch(void* const* d_in, const int* in_sizes, int n_in,
                              void* d_out, int out_size, void* d_ws, size_t ws_size,
                              hipStream_t stream) {
    const int*   coords = (const int*)d_in[0];
    const float* feats  = (const float*)d_in[1];
    const float* w1     = (const float*)d_in[2];
    const float* g1     = (const float*)d_in[3];
    const float* b1     = (const float*)d_in[4];
    const float* w3     = (const float*)d_in[5];
    const float* g2     = (const float*)d_in[6];
    const float* b2     = (const float*)d_in[7];
    const float* wout   = (const float*)d_in[8];
    float* out = (float*)d_out;

    char* ws = (char*)d_ws;
    int*    table_base = (int*)(ws);                              // 4.03 MB
    int*    table   = table_base + GUARD;
    int*    packed  = (int*)(ws + (4352u<<10));                   // 128 KB
    int*    keyb    = (int*)(ws + (4608u<<10));                   // 128 KB
    int*    nbr     = (int*)(ws + (4864u<<10));                   // 1 MB
    int*    flagcnt = (int*)(ws + (5888u<<10));                   // 4 B
    int*    flaglist= (int*)(ws + (5892u<<10));                   // 128 KB
    float*  gsum2   = (float*)(ws + (6416u<<10));                 // 1 KB (BN2 direct sums)
    float*  gsum1   = (float*)(ws + (6420u<<10));                 // 8 KB (BN1, 8 replicas x 256)
    ushort* w3f     = (ushort*)(ws + (6656u<<10));                // 0.88 MB (ends 7520K)
    ushort* hb      = (ushort*)(ws + (7680u<<10));                // 8 MB; hb-128 = 256B zero row
    float*  h       = (float*)(ws + (15872u<<10));                // 16 MB
    float*  h2      = h;   // aliased: h is dead once hb is written, conv3 reads only hb

    static bool conv3_attr_set = false;
    if (!conv3_attr_set) {
        hipFuncSetAttribute(reinterpret_cast<const void*>(&conv3_mfma_kernel),
                            hipFuncAttributeMaxDynamicSharedMemorySize, CONV3_LDS);
        conv3_attr_set = true;
    }

    hipMemsetAsync(table_base, 0xFF, (TBL + GUARD) * sizeof(int), stream);
    prep_pack_kernel <<<344, 256, 0, stream>>>(coords, table, packed, keyb, w3, w3f,
                                               gsum1, gsum2, flagcnt,
                                               (unsigned int*)(hb - 128));
    knn_window_kernel<<<N_/64, 256, 0, stream>>>(table, keyb, nbr, flagcnt, flaglist);
    knn_bf_kernel    <<<256, 256, 0, stream>>>(packed, flagcnt, flaglist, nbr);
    h1_kernel        <<<N_/16, 256, 0, stream>>>(feats, nbr, w1, h, gsum1);
    bnrelu_bf16_kernel<<<(N_*H_/4)/256, 256, 0, stream>>>(h, gsum1, g1, b1, hb);
    conv3_mfma_kernel<<<N_/128, 512, CONV3_LDS, stream>>>(hb, w3f, table, keyb, h2, gsum2);
    out_kernel       <<<N_/128, 256, 0, stream>>>(h2, wout, gsum2, g2, b2, out);
}